// Round 2
// baseline (315.638 us; speedup 1.0000x reference)
//
#include <hip/hip_runtime.h>

// B=8, L=2048, C=256, D=32. Four attentions (ecg/pcg intra/inter),
// out = concat(inter + scalar*intra) -> (8,2048,512) f32.
//
// Pipeline:
//   1) hipMemsetAsync(d_out, 0); all four attentions atomically accumulate.
//   2) deint_kernel : x f32 interleaved -> xe, xp bf16 [16384][256]
//   3) proj_kernel  : xe/xp @ w -> bf16 Q[4] (pre-scaled log2e/sqrt(32)), K[4], V^T[4]
//   4) flash_kernel : 1024 blocks x 256 thr (4 waves = 2 q-subtiles x 2 vcol-halves).
//      OCCUPANCY-TUNED: wave tile 32q x 128 vcols (acc[4] = 64 AGPR), key-tile 32
//      (LDS 2x16KB dbuf = 32KB) -> 3 blocks/CU, 12 waves/CU (__launch_bounds__(256,3)),
//      vs previous 2 blocks/8 waves at acc[8]/64KB. S^T trick: A=K,B=Q so each lane
//      holds all keys of its query; P -> MFMA-A layout via lane-pair shfl_xor(32).
//      Fixed-max softmax in log2 domain; scalar den accumulator + shfl broadcast.
//      S is computed per vcol-half wave (duplicated x2; S is 20% of MFMA).
//      Epilogue: unsafeAtomicAdd.

typedef __bf16 v8bf __attribute__((ext_vector_type(8)));
typedef float  v16f __attribute__((ext_vector_type(16)));
typedef unsigned int u32;

typedef __attribute__((address_space(1))) const void gvoid;
typedef __attribute__((address_space(3))) void svoid;

#define QSCALE 0.25500526817276613f  // log2(e)/sqrt(32)

union frag_u { u32 d[4]; v8bf v; };
union pk_u { unsigned short s[2]; u32 d; };

static __device__ inline u32 pack_bf16(float x, float y) {
  pk_u u;
  __bf16 a = (__bf16)x, b = (__bf16)y;
  u.s[0] = *(unsigned short*)&a;
  u.s[1] = *(unsigned short*)&b;
  return u.d;
}

// ---------------------------------------------------------------- deinterleave
__global__ __launch_bounds__(256) void deint_kernel(const float* __restrict__ x,
                                                    __bf16* __restrict__ xe,
                                                    __bf16* __restrict__ xp) {
  const size_t i = (size_t)blockIdx.x * 256 + threadIdx.x;
  const float4* xin = (const float4*)(x + i * 16);
  float4 a = xin[0], b = xin[1], c = xin[2], d = xin[3];
  v8bf ev, pv;
  ev[0]=(__bf16)a.x; ev[1]=(__bf16)a.z; ev[2]=(__bf16)b.x; ev[3]=(__bf16)b.z;
  ev[4]=(__bf16)c.x; ev[5]=(__bf16)c.z; ev[6]=(__bf16)d.x; ev[7]=(__bf16)d.z;
  pv[0]=(__bf16)a.y; pv[1]=(__bf16)a.w; pv[2]=(__bf16)b.y; pv[3]=(__bf16)b.w;
  pv[4]=(__bf16)c.y; pv[5]=(__bf16)c.w; pv[6]=(__bf16)d.y; pv[7]=(__bf16)d.w;
  *(v8bf*)(xe + i * 8) = ev;
  *(v8bf*)(xp + i * 8) = pv;
}

// ---------------------------------------------------------------- projections
struct ProjArgs {
  const __bf16* xe;
  const __bf16* xp;
  const float* w[12];
  __bf16* q[4];
  __bf16* k[4];
  __bf16* vt[4];
};

// grid (20 jobs, 128 row-tiles of 128), block 256 (4 waves, 32 rows each, 64 cols).
__global__ __launch_bounds__(256) void proj_kernel(ProjArgs pa) {
  const int job = blockIdx.x;
  const int rb  = blockIdx.y * 128;
  const int tid = threadIdx.x;
  const int lane = tid & 63, w = tid >> 6;
  const int l31 = lane & 31, lh = lane >> 5;
  const int l7 = lane & 7, l8 = lane >> 3;

  __shared__ __bf16 lds_b[64][264];      // 64 n x 256 k (+8 pad, 528B rows)
  __shared__ __bf16 lds_a[2][128 * 64];  // dbuf BK=64, swizzled 128B rows

  int src, dout, wc0[2], vcol0 = 0, vmode = 0;
  const float* wp[2];
  __bf16* dqk[2] = {nullptr, nullptr};
  __bf16* vdst = nullptr;
  float sc = 1.0f;
  if (job < 4) {
    dout = 32; wc0[0] = 0; wc0[1] = 0;
    switch (job) {
      case 0: src=0; wp[0]=pa.w[0]; wp[1]=pa.w[3];  dqk[0]=pa.q[0]; dqk[1]=pa.q[1]; sc=QSCALE; break;
      case 1: src=0; wp[0]=pa.w[1]; wp[1]=pa.w[10]; dqk[0]=pa.k[0]; dqk[1]=pa.k[3]; break;
      case 2: src=1; wp[0]=pa.w[6]; wp[1]=pa.w[9];  dqk[0]=pa.q[2]; dqk[1]=pa.q[3]; sc=QSCALE; break;
      default:src=1; wp[0]=pa.w[4]; wp[1]=pa.w[7];  dqk[0]=pa.k[1]; dqk[1]=pa.k[2]; break;
    }
  } else {
    const int vi = (job - 4) >> 2, t = (job - 4) & 3;
    const int widx = (vi==0) ? 2 : (vi==1) ? 11 : (vi==2) ? 5 : 8;   // w3,w12,w6,w9
    const int vbuf = (vi==0) ? 0 : (vi==1) ? 3  : (vi==2) ? 1 : 2;   // V0,V3,V1,V2
    dout = 256; vmode = 1; src = vi >> 1;                            // e,e,p,p
    wp[0] = pa.w[widx]; wp[1] = pa.w[widx];
    wc0[0] = t*64; wc0[1] = t*64 + 32;
    vcol0 = t*64; vdst = pa.vt[vbuf];
  }

  // stage B transposed (once): lds_b[n][k] = w[k][c0+n]
  for (int h = 0; h < 2; ++h) {
    const float* wgt = wp[h]; const int c0 = wc0[h];
    for (int i = tid; i < 32*256; i += 256) {
      int n = i & 31, kk = i >> 5;
      lds_b[h*32 + n][kk] = (__bf16)wgt[(size_t)kk*dout + c0 + n];
    }
  }

  const __bf16* X = src ? pa.xp : pa.xe;
  const char* agbase = (const char*)(X + (size_t)rb*256) + (size_t)(l7 ^ l8)*16
                     + (size_t)l8*512;

  // stage A slice kb into buf (rows (w*4+i)*8 + l8, swizzled chunk l7^l8)
#define STAGE_A(buf, kb)                                                        \
  {                                                                             \
    const char* g = agbase + (size_t)(kb)*128;                                  \
    _Pragma("unroll")                                                           \
    for (int i = 0; i < 4; ++i)                                                 \
      __builtin_amdgcn_global_load_lds(                                         \
          (gvoid*)(g + (size_t)(w*4 + i)*8*512),                                \
          (svoid*)&lds_a[buf][((w*4 + i)*8)*64 + lane*8], 16, 0, 0);            \
  }

  STAGE_A(0, 0)
  __syncthreads();

  v16f acc[2];
#pragma unroll
  for (int n = 0; n < 2; ++n)
#pragma unroll
    for (int i = 0; i < 16; ++i) acc[n][i] = 0.f;

  for (int kb = 0; kb < 4; ++kb) {
    if (kb < 3) STAGE_A((kb + 1) & 1, kb + 1)
    const __bf16* ab = &lds_a[kb & 1][0];
#pragma unroll
    for (int kk = 0; kk < 4; ++kk) {
      const v8bf af = *(const v8bf*)&ab[(w*32 + l31)*64 + (((kk*2 + lh) ^ (l31 & 7))*8)];
#pragma unroll
      for (int nt = 0; nt < 2; ++nt) {
        const v8bf bf = *(const v8bf*)&lds_b[nt*32 + l31][kb*64 + kk*16 + lh*8];
        acc[nt] = __builtin_amdgcn_mfma_f32_32x32x16_bf16(af, bf, acc[nt], 0, 0, 0);
      }
    }
    __syncthreads();
  }

  if (!vmode) {
    // Q/K row-major [16384][32]
#pragma unroll
    for (int nt = 0; nt < 2; ++nt) {
      __bf16* dst = dqk[nt];
#pragma unroll
      for (int r = 0; r < 16; ++r) {
        const int row = rb + w*32 + (r & 3) + 8*(r >> 2) + 4*lh;
        dst[(size_t)row*32 + l31] = (__bf16)(acc[nt][r] * sc);
      }
    }
  } else {
    // V: transpose through LDS (reuse lds_a), write V^T[b][vcol][l] coalesced
    __bf16 (*lds_t)[136] = (__bf16 (*)[136])&lds_a[0][0];  // 64 x 136 (272B rows)
#pragma unroll
    for (int nt = 0; nt < 2; ++nt) {
#pragma unroll
      for (int r = 0; r < 16; ++r) {
        const int row = w*32 + (r & 3) + 8*(r >> 2) + 4*lh;
        lds_t[nt*32 + l31][row] = (__bf16)acc[nt][r];
      }
    }
    __syncthreads();
    const int bb = rb >> 11, ll0 = rb & 2047;
    for (int i = tid; i < 1024; i += 256) {
      const int vrow = i >> 4, seg = i & 15;
      *(int4*)&vdst[((size_t)(bb*256 + vcol0 + vrow))*2048 + ll0 + seg*8] =
          *(const int4*)&lds_t[vrow][seg*8];
    }
  }
}

// ---------------------------------------------------------------- flash attention
struct FlashArgs {
  const __bf16* q[4];
  const __bf16* k[4];
  const __bf16* v[4];
  const float* alpha;
  const float* gamma;
  float* out;
};

// 1024 blocks x 256 thr. flat = pair + 32*qb (pair%8 pins an (att,bb) to one XCD).
// Block: 64 q rows x 256 vcols; wave (qsub = w>>1, vh = w&1) does 32q x 128 vcols.
// 64 key-tiles of 32 keys; V tile (256 vcols x 32 keys) dbuf-staged via
// global_load_lds into chunk-XOR-swizzled LDS, shared by the 4 waves.
__global__ __launch_bounds__(256, 3) void flash_kernel(FlashArgs fa) {
  const int flat = blockIdx.x;
  const int pair = flat & 31, qb = flat >> 5;
  const int att = pair & 3, bb = pair >> 2;
  const int tid = threadIdx.x;
  const int lane = tid & 63, w = tid >> 6;
  const int qsub = w >> 1, vh = w & 1;
  const int l31 = lane & 31, lh = lane >> 5;
  const int swz3 = l31 & 3;

  __shared__ __bf16 v_lds[2][8192];  // 2 x (256 vrows x 32 keys), 64B rows

  const __bf16* Q  = fa.q[att] + (size_t)bb*2048*32;
  const __bf16* Kb = fa.k[att] + (size_t)bb*2048*32;
  const __bf16* Vb = fa.v[att] + (size_t)bb*256*2048;
  float scv = 1.0f;
  if (att == 0) scv = fa.alpha[0];
  if (att == 2) scv = fa.gamma[0];
  const int zcol = (att >> 1) * 256 + vh * 128;

  // Q B-frags (resident): B[n=q=l31][k=d = c*16 + lh*8 + j]
  const int qrow = qb*64 + qsub*32 + l31;
  const v8bf qf0 = *(const v8bf*)&Q[(size_t)qrow*32 + lh*8];
  const v8bf qf1 = *(const v8bf*)&Q[(size_t)qrow*32 + 16 + lh*8];

  // V staging: wave w covers vrows w*64..+63 in 4 issues of 16 rows.
  // LDS chunk c of row r holds global key-chunk c ^ (r&3)  (16B chunks, 4/row).
  const int srow = w*64 + (lane >> 2);
  const int schunk = (lane & 3) ^ ((lane >> 2) & 3);
  const char* vgbase = (const char*)Vb + (size_t)srow*4096 + (size_t)schunk*16;

#define STAGE_V(buf, kt)                                                        \
  {                                                                             \
    const char* g = vgbase + (size_t)(kt)*64;                                   \
    _Pragma("unroll")                                                           \
    for (int i = 0; i < 4; ++i)                                                 \
      __builtin_amdgcn_global_load_lds(                                         \
          (gvoid*)(g + (size_t)i*16*4096),                                      \
          (svoid*)&v_lds[buf][(w*64 + i*16)*32 + lane*8], 16, 0, 0);            \
  }

  int voff[2];
#pragma unroll
  for (int kc = 0; kc < 2; ++kc)
    voff[kc] = ((kc*2 + lh) ^ swz3) * 8;

  v16f acc[4];
#pragma unroll
  for (int n = 0; n < 4; ++n)
#pragma unroll
    for (int i = 0; i < 16; ++i) acc[n][i] = 0.f;

  float den_s = 0.f;        // per-lane row-sum accumulator (q = l31, this lh-half's keys)
  v8bf pf[2];               // P A-frags for the CURRENT kt (made one iteration ahead)
  v8bf kf0, kf1;
  v16f st;
  u32 pk[8];

  // K A-frags for 32-key tile kt_: A[m=key=l31][k=d]
#define LOADK(kt_)                                                              \
  {                                                                             \
    const size_t kr = (size_t)((kt_)*32 + l31) * 32;                            \
    kf0 = *(const v8bf*)&Kb[kr + lh*8];                                         \
    kf1 = *(const v8bf*)&Kb[kr + 16 + lh*8];                                    \
  }

  // S^T = K.Q^T (log2 domain): C[row=key][col=q]
#define SMFMA                                                                   \
  {                                                                             \
    _Pragma("unroll")                                                           \
    for (int i = 0; i < 16; ++i) st[i] = 0.f;                                   \
    st = __builtin_amdgcn_mfma_f32_32x32x16_bf16(kf0, qf0, st, 0, 0, 0);        \
    st = __builtin_amdgcn_mfma_f32_32x32x16_bf16(kf1, qf1, st, 0, 0, 0);        \
  }

  // P = exp2(S^T) into bf16-packed key-pair dwords; den_s accumulates row sums
#define EXPH                                                                    \
  _Pragma("unroll")                                                             \
  for (int i = 0; i < 8; ++i) {                                                 \
    const float e0 = __builtin_exp2f(st[2*i]);                                  \
    const float e1 = __builtin_exp2f(st[2*i + 1]);                              \
    den_s += e0 + e1;                                                           \
    pk[i] = pack_bf16(e0, e1);                                                  \
  }

  // P A-frags via lane-pair exchange (C-layout -> A-layout, no LDS round-trip).
#define XCHG                                                                    \
  _Pragma("unroll")                                                             \
  for (int f2 = 0; f2 < 2; ++f2) {                                              \
    const u32 keep0 = lh ? pk[f2*4 + 2] : pk[f2*4 + 0];                         \
    const u32 keep1 = lh ? pk[f2*4 + 3] : pk[f2*4 + 1];                         \
    const u32 send0 = lh ? pk[f2*4 + 0] : pk[f2*4 + 2];                         \
    const u32 send1 = lh ? pk[f2*4 + 1] : pk[f2*4 + 3];                         \
    const u32 recv0 = (u32)__shfl_xor((int)send0, 32, 64);                      \
    const u32 recv1 = (u32)__shfl_xor((int)send1, 32, 64);                      \
    frag_u fu;                                                                  \
    fu.d[0] = lh ? recv0 : keep0;                                               \
    fu.d[1] = lh ? recv1 : keep1;                                               \
    fu.d[2] = lh ? keep0 : recv0;                                               \
    fu.d[3] = lh ? keep1 : recv1;                                               \
    pf[f2] = fu.v;                                                              \
  }

  // one kc-block of PV: 4 MFMAs over this wave's 4 vcol tiles
#define PVBLK(kc_, vb_)                                                         \
  _Pragma("unroll")                                                             \
  for (int nt = 0; nt < 4; ++nt) {                                              \
    const v8bf vf = *(const v8bf*)&vb_[(vh*128 + nt*32 + l31)*32 + voff[kc_]];  \
    acc[nt] = __builtin_amdgcn_mfma_f32_32x32x16_bf16(pf[kc_], vf, acc[nt], 0, 0, 0); \
  }

  // prologue: stage V(0), compute P(0) while staging is in flight
  STAGE_V(0, 0)
  LOADK(0)
  SMFMA
  EXPH
  XCHG
  __syncthreads();  // V(0) staged

  for (int kt = 0; kt < 63; ++kt) {
    const int cur = kt & 1;
    LOADK(kt + 1)              // K latency hidden under PVBLK(0)
    STAGE_V(cur ^ 1, kt + 1)   // lands by end-of-iteration barrier
    const __bf16* vb = &v_lds[cur][0];

    PVBLK(0, vb)
    SMFMA                      // S(kt+1): independent of PV(kt)
    PVBLK(1, vb)
    EXPH                       // softmax VALU hides under PV MFMA issue
    XCHG                       // pf consumed by PVBLK(0/1) above; safe to overwrite

    __syncthreads();           // all waves done with v_lds[cur]; V(kt+1) staged
  }

  {
    // kt=63: PV only (cur = 1)
    const __bf16* vb = &v_lds[1][0];
    PVBLK(0, vb)
    PVBLK(1, vb)
  }

  // epilogue: den[q] = this half's sum + partner half's sum; broadcast by lane
  const float den_full = den_s + __shfl_xor(den_s, 32, 64);
  float* outp = fa.out + (size_t)(bb*2048 + qb*64 + qsub*32) * 512 + zcol;
#pragma unroll
  for (int r = 0; r < 16; ++r) {
    const int row = (r & 3) + 8*(r >> 2) + 4*lh;
    const float f = scv / __shfl(den_full, row, 64);
#pragma unroll
    for (int nt = 0; nt < 4; ++nt)
      unsafeAtomicAdd(&outp[(size_t)row*512 + nt*32 + l31], acc[nt][r] * f);
  }
}

// ---------------------------------------------------------------- launch
extern "C" void kernel_launch(void* const* d_in, const int* in_sizes, int n_in,
                              void* d_out, int out_size, void* d_ws, size_t ws_size,
                              hipStream_t stream) {
  (void)in_sizes; (void)n_in; (void)out_size; (void)ws_size;

  __bf16* wsp = (__bf16*)d_ws;
  const size_t XE = (size_t)16384 * 256;
  const size_t QK = (size_t)16384 * 32;
  const size_t VT = (size_t)8 * 256 * 2048;

  __bf16* xe = wsp;
  __bf16* xp = wsp + XE;

  ProjArgs pa;
  pa.xe = xe; pa.xp = xp;
  const float* x = (const float*)d_in[0];
  for (int i = 0; i < 12; ++i) pa.w[i] = (const float*)d_in[1 + i];
  __bf16* base = wsp + 2*XE;
  for (int i = 0; i < 4; ++i) pa.q[i]  = base + (size_t)i * QK;
  for (int i = 0; i < 4; ++i) pa.k[i]  = base + (size_t)(4 + i) * QK;
  for (int i = 0; i < 4; ++i) pa.vt[i] = base + 8*QK + (size_t)i * VT;

  hipMemsetAsync(d_out, 0, (size_t)8*2048*512*4, stream);
  hipLaunchKernelGGL(deint_kernel, dim3(2048), dim3(256), 0, stream, x, xe, xp);
  hipLaunchKernelGGL(proj_kernel, dim3(20, 128), dim3(256), 0, stream, pa);

  FlashArgs fl;
  for (int i = 0; i < 4; ++i) { fl.q[i] = pa.q[i]; fl.k[i] = pa.k[i]; fl.v[i] = pa.vt[i]; }
  fl.alpha = (const float*)d_in[13];
  fl.gamma = (const float*)d_in[14];
  fl.out = (float*)d_out;
  hipLaunchKernelGGL(flash_kernel, dim3(1024), dim3(256), 0, stream, fl);
}

// Round 3
// 292.914 us; speedup vs baseline: 1.0776x; 1.0776x over previous
//
#include <hip/hip_runtime.h>

// B=8, L=2048, C=256, D=32. Four attentions (ecg/pcg intra/inter),
// out = concat(inter + scalar*intra) -> (8,2048,512) f32.
//
// Pipeline:
//   1) hipMemsetAsync(d_out, 0); all four attentions atomically accumulate.
//   2) deint_kernel : x f32 interleaved -> xe, xp bf16 [16384][256]
//   3) proj_kernel  : xe/xp @ w -> bf16 Q[4] (pre-scaled log2e/sqrt(32)), K[4], V^T[4]
//   4) flash_kernel : 512 blocks x 256 thr (4 waves = 4 q-subtiles, 64-key tiles).
//      V tile stored in LDS in MFMA-B-FRAGMENT SLOT ORDER: slot=(nt*8+kc2)*32+v5,
//      so every PV ds_read_b128 is 64 lanes x contiguous 16B (ZERO bank conflicts,
//      all offsets immediate). Staged via global_load_lds with per-lane global
//      addresses (32 rows x 32B segments, L2-resident V).
//      S^T trick: A=K,B=Q so each lane holds all keys of its query; P -> MFMA-A
//      layout via v_permlane32_swap_b32 (1 instr replaces shfl+cndmask dance).
//      Fixed-max softmax in log2 domain; scalar den accumulator + shfl broadcast.
//      Software-pipelined: S(kt+1)+softmax interleaved into PV(kt) MFMA stream.
//      Epilogue: unsafeAtomicAdd.

typedef __bf16 v8bf __attribute__((ext_vector_type(8)));
typedef float  v16f __attribute__((ext_vector_type(16)));
typedef unsigned int u32;

typedef __attribute__((address_space(1))) const void gvoid;
typedef __attribute__((address_space(3))) void svoid;

#define QSCALE 0.25500526817276613f  // log2(e)/sqrt(32)

union frag_u { u32 d[4]; v8bf v; };
union pk_u { unsigned short s[2]; u32 d; };

static __device__ inline u32 pack_bf16(float x, float y) {
  pk_u u;
  __bf16 a = (__bf16)x, b = (__bf16)y;
  u.s[0] = *(unsigned short*)&a;
  u.s[1] = *(unsigned short*)&b;
  return u.d;
}

// ---------------------------------------------------------------- deinterleave
__global__ __launch_bounds__(256) void deint_kernel(const float* __restrict__ x,
                                                    __bf16* __restrict__ xe,
                                                    __bf16* __restrict__ xp) {
  const size_t i = (size_t)blockIdx.x * 256 + threadIdx.x;
  const float4* xin = (const float4*)(x + i * 16);
  float4 a = xin[0], b = xin[1], c = xin[2], d = xin[3];
  v8bf ev, pv;
  ev[0]=(__bf16)a.x; ev[1]=(__bf16)a.z; ev[2]=(__bf16)b.x; ev[3]=(__bf16)b.z;
  ev[4]=(__bf16)c.x; ev[5]=(__bf16)c.z; ev[6]=(__bf16)d.x; ev[7]=(__bf16)d.z;
  pv[0]=(__bf16)a.y; pv[1]=(__bf16)a.w; pv[2]=(__bf16)b.y; pv[3]=(__bf16)b.w;
  pv[4]=(__bf16)c.y; pv[5]=(__bf16)c.w; pv[6]=(__bf16)d.y; pv[7]=(__bf16)d.w;
  *(v8bf*)(xe + i * 8) = ev;
  *(v8bf*)(xp + i * 8) = pv;
}

// ---------------------------------------------------------------- projections
struct ProjArgs {
  const __bf16* xe;
  const __bf16* xp;
  const float* w[12];
  __bf16* q[4];
  __bf16* k[4];
  __bf16* vt[4];
};

// grid (20 jobs, 128 row-tiles of 128), block 256 (4 waves, 32 rows each, 64 cols).
__global__ __launch_bounds__(256) void proj_kernel(ProjArgs pa) {
  const int job = blockIdx.x;
  const int rb  = blockIdx.y * 128;
  const int tid = threadIdx.x;
  const int lane = tid & 63, w = tid >> 6;
  const int l31 = lane & 31, lh = lane >> 5;
  const int l7 = lane & 7, l8 = lane >> 3;

  __shared__ __bf16 lds_b[64][264];      // 64 n x 256 k (+8 pad, 528B rows)
  __shared__ __bf16 lds_a[2][128 * 64];  // dbuf BK=64, swizzled 128B rows

  int src, dout, wc0[2], vcol0 = 0, vmode = 0;
  const float* wp[2];
  __bf16* dqk[2] = {nullptr, nullptr};
  __bf16* vdst = nullptr;
  float sc = 1.0f;
  if (job < 4) {
    dout = 32; wc0[0] = 0; wc0[1] = 0;
    switch (job) {
      case 0: src=0; wp[0]=pa.w[0]; wp[1]=pa.w[3];  dqk[0]=pa.q[0]; dqk[1]=pa.q[1]; sc=QSCALE; break;
      case 1: src=0; wp[0]=pa.w[1]; wp[1]=pa.w[10]; dqk[0]=pa.k[0]; dqk[1]=pa.k[3]; break;
      case 2: src=1; wp[0]=pa.w[6]; wp[1]=pa.w[9];  dqk[0]=pa.q[2]; dqk[1]=pa.q[3]; sc=QSCALE; break;
      default:src=1; wp[0]=pa.w[4]; wp[1]=pa.w[7];  dqk[0]=pa.k[1]; dqk[1]=pa.k[2]; break;
    }
  } else {
    const int vi = (job - 4) >> 2, t = (job - 4) & 3;
    const int widx = (vi==0) ? 2 : (vi==1) ? 11 : (vi==2) ? 5 : 8;   // w3,w12,w6,w9
    const int vbuf = (vi==0) ? 0 : (vi==1) ? 3  : (vi==2) ? 1 : 2;   // V0,V3,V1,V2
    dout = 256; vmode = 1; src = vi >> 1;                            // e,e,p,p
    wp[0] = pa.w[widx]; wp[1] = pa.w[widx];
    wc0[0] = t*64; wc0[1] = t*64 + 32;
    vcol0 = t*64; vdst = pa.vt[vbuf];
  }

  // stage B transposed (once): lds_b[n][k] = w[k][c0+n]
  for (int h = 0; h < 2; ++h) {
    const float* wgt = wp[h]; const int c0 = wc0[h];
    for (int i = tid; i < 32*256; i += 256) {
      int n = i & 31, kk = i >> 5;
      lds_b[h*32 + n][kk] = (__bf16)wgt[(size_t)kk*dout + c0 + n];
    }
  }

  const __bf16* X = src ? pa.xp : pa.xe;
  const char* agbase = (const char*)(X + (size_t)rb*256) + (size_t)(l7 ^ l8)*16
                     + (size_t)l8*512;

  // stage A slice kb into buf (rows (w*4+i)*8 + l8, swizzled chunk l7^l8)
#define STAGE_A(buf, kb)                                                        \
  {                                                                             \
    const char* g = agbase + (size_t)(kb)*128;                                  \
    _Pragma("unroll")                                                           \
    for (int i = 0; i < 4; ++i)                                                 \
      __builtin_amdgcn_global_load_lds(                                         \
          (gvoid*)(g + (size_t)(w*4 + i)*8*512),                                \
          (svoid*)&lds_a[buf][((w*4 + i)*8)*64 + lane*8], 16, 0, 0);            \
  }

  STAGE_A(0, 0)
  __syncthreads();

  v16f acc[2];
#pragma unroll
  for (int n = 0; n < 2; ++n)
#pragma unroll
    for (int i = 0; i < 16; ++i) acc[n][i] = 0.f;

  for (int kb = 0; kb < 4; ++kb) {
    if (kb < 3) STAGE_A((kb + 1) & 1, kb + 1)
    const __bf16* ab = &lds_a[kb & 1][0];
#pragma unroll
    for (int kk = 0; kk < 4; ++kk) {
      const v8bf af = *(const v8bf*)&ab[(w*32 + l31)*64 + (((kk*2 + lh) ^ (l31 & 7))*8)];
#pragma unroll
      for (int nt = 0; nt < 2; ++nt) {
        const v8bf bf = *(const v8bf*)&lds_b[nt*32 + l31][kb*64 + kk*16 + lh*8];
        acc[nt] = __builtin_amdgcn_mfma_f32_32x32x16_bf16(af, bf, acc[nt], 0, 0, 0);
      }
    }
    __syncthreads();
  }

  if (!vmode) {
    // Q/K row-major [16384][32]
#pragma unroll
    for (int nt = 0; nt < 2; ++nt) {
      __bf16* dst = dqk[nt];
#pragma unroll
      for (int r = 0; r < 16; ++r) {
        const int row = rb + w*32 + (r & 3) + 8*(r >> 2) + 4*lh;
        dst[(size_t)row*32 + l31] = (__bf16)(acc[nt][r] * sc);
      }
    }
  } else {
    // V: transpose through LDS (reuse lds_a), write V^T[b][vcol][l] coalesced
    __bf16 (*lds_t)[136] = (__bf16 (*)[136])&lds_a[0][0];  // 64 x 136 (272B rows)
#pragma unroll
    for (int nt = 0; nt < 2; ++nt) {
#pragma unroll
      for (int r = 0; r < 16; ++r) {
        const int row = w*32 + (r & 3) + 8*(r >> 2) + 4*lh;
        lds_t[nt*32 + l31][row] = (__bf16)acc[nt][r];
      }
    }
    __syncthreads();
    const int bb = rb >> 11, ll0 = rb & 2047;
    for (int i = tid; i < 1024; i += 256) {
      const int vrow = i >> 4, seg = i & 15;
      *(int4*)&vdst[((size_t)(bb*256 + vcol0 + vrow))*2048 + ll0 + seg*8] =
          *(const int4*)&lds_t[vrow][seg*8];
    }
  }
}

// ---------------------------------------------------------------- flash attention
struct FlashArgs {
  const __bf16* q[4];
  const __bf16* k[4];
  const __bf16* v[4];
  const float* alpha;
  const float* gamma;
  float* out;
};

// 512 blocks x 256 thr. flat = pair + 32*qt (pair%8 pins an (att,bb) to one XCD).
// Wave: 32 q x 256 vcols over 32 kt of 64 keys. V tile dbuf-staged via
// global_load_lds into FRAGMENT-SLOT-ORDER LDS (conflict-free ds_read_b128):
//   slot(nt, kc2, v5) = (nt*8 + kc2)*32 + v5   (16B slots; kc2 = 8-key chunk)
// PV read for (nt,kc): slots nt*256 + kc*64 + lane  -> contiguous 1KB, lane*16B.
__global__ __launch_bounds__(256, 2) void flash_kernel(FlashArgs fa) {
  const int flat = blockIdx.x;
  const int pair = flat & 31, qt = flat >> 5;
  const int att = pair & 3, bb = pair >> 2;
  const int tid = threadIdx.x;
  const int lane = tid & 63, w = tid >> 6;
  const int l31 = lane & 31, lh = lane >> 5;

  __shared__ __bf16 v_lds[2][16384];  // 2 x 2048 slots x 16B, frag order

  const __bf16* Q  = fa.q[att] + (size_t)bb*2048*32;
  const __bf16* Kb = fa.k[att] + (size_t)bb*2048*32;
  const __bf16* Vb = fa.v[att] + (size_t)bb*256*2048;
  float scv = 1.0f;
  if (att == 0) scv = fa.alpha[0];
  if (att == 2) scv = fa.gamma[0];
  const int zcol = (att >> 1) * 256;

  // Q B-frags (resident): B[n=q=l31][k=d = c*16 + lh*8 + j]
  const int qrow = qt*128 + w*32 + l31;
  const v8bf qf0 = *(const v8bf*)&Q[(size_t)qrow*32 + lh*8];
  const v8bf qf1 = *(const v8bf*)&Q[(size_t)qrow*32 + 16 + lh*8];

  // V staging, frag-slot order. Wave w stages slots [512w, 512w+512), 8 issues.
  // Instr i, lane: slot = 512w + 64i + lane -> nt = 2w+(i>>2), kc2 = 2(i&3)+lh,
  // v5 = l31. Global src = Vb + (nt*32+l31)*4096 + kt*128 + kc2*16.
  const char* vgbase = (const char*)Vb + (size_t)(w*64 + l31)*4096 + (size_t)lh*16;

#define STAGE_V(buf, kt_)                                                       \
  {                                                                             \
    const char* g = vgbase + (size_t)(kt_)*128;                                 \
    _Pragma("unroll")                                                           \
    for (int i = 0; i < 8; ++i)                                                 \
      __builtin_amdgcn_global_load_lds(                                         \
          (gvoid*)(g + (size_t)(i >> 2)*131072 + (size_t)(i & 3)*32),           \
          (svoid*)&v_lds[buf][(512*w + 64*i)*8 + lane*8], 16, 0, 0);            \
  }

  v16f acc[8];
#pragma unroll
  for (int n = 0; n < 8; ++n)
#pragma unroll
    for (int i = 0; i < 16; ++i) acc[n][i] = 0.f;

  float den_s = 0.f;        // per-lane row-sum accumulator (q = l31, this lh-half's keys)
  v8bf pf[4];               // P A-frags for the CURRENT kt (made one iteration ahead)
  v8bf kf00, kf01, kf10, kf11;
  v16f st0, st1;
  u32 pk0[8], pk1[8];

  // K A-frags for tile kt_: A[m=key = t*32+l31][k=d]
#define LOADK(kt_)                                                              \
  {                                                                             \
    const int kb_ = (kt_) * 64;                                                 \
    kf00 = *(const v8bf*)&Kb[((size_t)(kb_ +      l31))*32 +      lh*8];        \
    kf01 = *(const v8bf*)&Kb[((size_t)(kb_ +      l31))*32 + 16 + lh*8];        \
    kf10 = *(const v8bf*)&Kb[((size_t)(kb_ + 32 + l31))*32 +      lh*8];        \
    kf11 = *(const v8bf*)&Kb[((size_t)(kb_ + 32 + l31))*32 + 16 + lh*8];        \
  }

  // S^T = K.Q^T (log2 domain): C[row=key][col=q]
#define SMFMA                                                                   \
  {                                                                             \
    _Pragma("unroll")                                                           \
    for (int i = 0; i < 16; ++i) { st0[i] = 0.f; st1[i] = 0.f; }                \
    st0 = __builtin_amdgcn_mfma_f32_32x32x16_bf16(kf00, qf0, st0, 0, 0, 0);     \
    st0 = __builtin_amdgcn_mfma_f32_32x32x16_bf16(kf01, qf1, st0, 0, 0, 0);     \
    st1 = __builtin_amdgcn_mfma_f32_32x32x16_bf16(kf10, qf0, st1, 0, 0, 0);     \
    st1 = __builtin_amdgcn_mfma_f32_32x32x16_bf16(kf11, qf1, st1, 0, 0, 0);     \
  }

  // P = exp2(S^T) into bf16-packed key-pair dwords; den_s accumulates row sums
#define EXPH(st_, pk_)                                                          \
  _Pragma("unroll")                                                             \
  for (int i = 0; i < 8; ++i) {                                                 \
    const float e0 = __builtin_exp2f(st_[2*i]);                                 \
    const float e1 = __builtin_exp2f(st_[2*i + 1]);                             \
    den_s += e0 + e1;                                                           \
    pk_[i] = pack_bf16(e0, e1);                                                 \
  }

  // P C-layout -> A-layout via lane-half exchange. v_permlane32_swap_b32
  // (vdst.upper <-> vsrc.lower) on pairs (pk[j], pk[j+2]) yields A-frag dwords
  // d[j] (=a') and d[j+2] (=b') for all lanes -- identical data movement to the
  // old shfl_xor(32)+cndmask sequence, 2 VALU ops per 4 dwords.
#define XCHG(pk_, o_)                                                           \
  _Pragma("unroll")                                                             \
  for (int f2 = 0; f2 < 2; ++f2) {                                              \
    u32 a0 = pk_[f2*4 + 0], b0 = pk_[f2*4 + 2];                                 \
    u32 a1 = pk_[f2*4 + 1], b1 = pk_[f2*4 + 3];                                 \
    asm("v_permlane32_swap_b32 %0, %1" : "+v"(a0), "+v"(b0));                   \
    asm("v_permlane32_swap_b32 %0, %1" : "+v"(a1), "+v"(b1));                   \
    frag_u fu;                                                                  \
    fu.d[0] = a0; fu.d[1] = a1; fu.d[2] = b0; fu.d[3] = b1;                     \
    pf[(o_) + f2] = fu.v;                                                       \
  }

  // one kc-block of PV: 8 MFMAs over 8 vcol tiles; reads contiguous, offsets imm
#define PVBLK(kc_, vb_)                                                         \
  _Pragma("unroll")                                                             \
  for (int nt = 0; nt < 8; ++nt) {                                              \
    const v8bf vf = *(const v8bf*)&vb_[nt*2048 + (kc_)*512 + lane*8];           \
    acc[nt] = __builtin_amdgcn_mfma_f32_32x32x16_bf16(pf[kc_], vf, acc[nt], 0, 0, 0); \
  }

  // prologue: K first (its wait leaves stage loads in flight), stage V(0),
  // compute P(0) while staging is in flight
  LOADK(0)
  STAGE_V(0, 0)
  SMFMA
  EXPH(st0, pk0)
  EXPH(st1, pk1)
  XCHG(pk0, 0)
  XCHG(pk1, 2)
  __syncthreads();  // V(0) staged

  for (int kt = 0; kt < 31; ++kt) {
    const int cur = kt & 1;
    LOADK(kt + 1)              // issued before stage: kf wait = vmcnt(8), no drain
    STAGE_V(cur ^ 1, kt + 1)   // lands by end-of-iteration barrier
    const __bf16* vb = &v_lds[cur][0];

    PVBLK(0, vb)
    SMFMA                      // S(kt+1): independent of PV(kt)
    PVBLK(1, vb)
    EXPH(st0, pk0)             // softmax VALU hides under PV MFMA issue
    PVBLK(2, vb)
    EXPH(st1, pk1)
    XCHG(pk0, 0)               // pf[0..1] already consumed by PVBLK(0/1)
    PVBLK(3, vb)
    XCHG(pk1, 2)               // pf[2..3] consumed by PVBLK(2/3)

    __syncthreads();           // all waves done with v_lds[cur]; V(kt+1) staged
  }

  {
    // kt=31: PV only (cur = 1)
    const __bf16* vb = &v_lds[1][0];
    PVBLK(0, vb)
    PVBLK(1, vb)
    PVBLK(2, vb)
    PVBLK(3, vb)
  }

  // epilogue: den[q] = this half's sum + partner half's sum; broadcast by lane
  const float den_full = den_s + __shfl_xor(den_s, 32, 64);
  float* outp = fa.out + (size_t)(bb*2048 + qt*128 + w*32) * 512 + zcol;
#pragma unroll
  for (int r = 0; r < 16; ++r) {
    const int row = (r & 3) + 8*(r >> 2) + 4*lh;
    const float f = scv / __shfl(den_full, row, 64);
#pragma unroll
    for (int nt = 0; nt < 8; ++nt)
      unsafeAtomicAdd(&outp[(size_t)row*512 + nt*32 + l31], acc[nt][r] * f);
  }
}

// ---------------------------------------------------------------- launch
extern "C" void kernel_launch(void* const* d_in, const int* in_sizes, int n_in,
                              void* d_out, int out_size, void* d_ws, size_t ws_size,
                              hipStream_t stream) {
  (void)in_sizes; (void)n_in; (void)out_size; (void)ws_size;

  __bf16* wsp = (__bf16*)d_ws;
  const size_t XE = (size_t)16384 * 256;
  const size_t QK = (size_t)16384 * 32;
  const size_t VT = (size_t)8 * 256 * 2048;

  __bf16* xe = wsp;
  __bf16* xp = wsp + XE;

  ProjArgs pa;
  pa.xe = xe; pa.xp = xp;
  const float* x = (const float*)d_in[0];
  for (int i = 0; i < 12; ++i) pa.w[i] = (const float*)d_in[1 + i];
  __bf16* base = wsp + 2*XE;
  for (int i = 0; i < 4; ++i) pa.q[i]  = base + (size_t)i * QK;
  for (int i = 0; i < 4; ++i) pa.k[i]  = base + (size_t)(4 + i) * QK;
  for (int i = 0; i < 4; ++i) pa.vt[i] = base + 8*QK + (size_t)i * VT;

  hipMemsetAsync(d_out, 0, (size_t)8*2048*512*4, stream);
  hipLaunchKernelGGL(deint_kernel, dim3(2048), dim3(256), 0, stream, x, xe, xp);
  hipLaunchKernelGGL(proj_kernel, dim3(20, 128), dim3(256), 0, stream, pa);

  FlashArgs fl;
  for (int i = 0; i < 4; ++i) { fl.q[i] = pa.q[i]; fl.k[i] = pa.k[i]; fl.v[i] = pa.vt[i]; }
  fl.alpha = (const float*)d_in[13];
  fl.gamma = (const float*)d_in[14];
  fl.out = (float*)d_out;
  hipLaunchKernelGGL(flash_kernel, dim3(512), dim3(256), 0, stream, fl);
}

// Round 4
// 283.842 us; speedup vs baseline: 1.1120x; 1.0320x over previous
//
#include <hip/hip_runtime.h>

// B=8, L=2048, C=256, D=32. Four attentions (ecg/pcg intra/inter),
// out = concat(inter + scalar*intra) -> (8,2048,512) f32.
//
// Pipeline:
//   1) hipMemsetAsync(d_out, 0); all four attentions atomically accumulate.
//   2) deint_kernel : x f32 interleaved -> xe, xp bf16 [16384][256]
//   3) proj_kernel  : xe/xp @ w -> bf16 Q[4] (pre-scaled log2e/sqrt(32)), K[4],
//      and V in GLOBAL FRAGMENT-SLOT ORDER Vf[bb][kt][slot]:
//        slot(nt,kc2,v5) = (nt*8+kc2)*32 + v5, 16B slots (8 keys), tile = 32KB.
//      The MFMA-B permutation is paid here (proj epilogue writes are 4KB-contiguous,
//      better than the old V^T strided writes) so flash's staging AND reads are
//      both perfectly linear.
//   4) flash_kernel : 512 blocks x 256 thr (4 waves = 4 q-subtiles, 64-key tiles).
//      V staged via global_load_lds: contiguous 1KB global per instr, linear LDS,
//      conflict-free contiguous ds_read_b128 with immediate offsets (0 bank conf).
//      S^T trick: A=K,B=Q so each lane holds all keys of its query; P -> MFMA-A
//      layout via v_permlane32_swap_b32. Fixed-max softmax in log2 domain;
//      scalar den accumulator + shfl broadcast. Software-pipelined: S(kt+1)+softmax
//      interleaved into PV(kt) MFMA stream. Epilogue: unsafeAtomicAdd.

typedef __bf16 v8bf __attribute__((ext_vector_type(8)));
typedef float  v16f __attribute__((ext_vector_type(16)));
typedef unsigned int u32;

typedef __attribute__((address_space(1))) const void gvoid;
typedef __attribute__((address_space(3))) void svoid;

#define QSCALE 0.25500526817276613f  // log2(e)/sqrt(32)

union frag_u { u32 d[4]; v8bf v; };
union pk_u { unsigned short s[2]; u32 d; };

static __device__ inline u32 pack_bf16(float x, float y) {
  pk_u u;
  __bf16 a = (__bf16)x, b = (__bf16)y;
  u.s[0] = *(unsigned short*)&a;
  u.s[1] = *(unsigned short*)&b;
  return u.d;
}

// ---------------------------------------------------------------- deinterleave
__global__ __launch_bounds__(256) void deint_kernel(const float* __restrict__ x,
                                                    __bf16* __restrict__ xe,
                                                    __bf16* __restrict__ xp) {
  const size_t i = (size_t)blockIdx.x * 256 + threadIdx.x;
  const float4* xin = (const float4*)(x + i * 16);
  float4 a = xin[0], b = xin[1], c = xin[2], d = xin[3];
  v8bf ev, pv;
  ev[0]=(__bf16)a.x; ev[1]=(__bf16)a.z; ev[2]=(__bf16)b.x; ev[3]=(__bf16)b.z;
  ev[4]=(__bf16)c.x; ev[5]=(__bf16)c.z; ev[6]=(__bf16)d.x; ev[7]=(__bf16)d.z;
  pv[0]=(__bf16)a.y; pv[1]=(__bf16)a.w; pv[2]=(__bf16)b.y; pv[3]=(__bf16)b.w;
  pv[4]=(__bf16)c.y; pv[5]=(__bf16)c.w; pv[6]=(__bf16)d.y; pv[7]=(__bf16)d.w;
  *(v8bf*)(xe + i * 8) = ev;
  *(v8bf*)(xp + i * 8) = pv;
}

// ---------------------------------------------------------------- projections
struct ProjArgs {
  const __bf16* xe;
  const __bf16* xp;
  const float* w[12];
  __bf16* q[4];
  __bf16* k[4];
  __bf16* vt[4];
};

// grid (20 jobs, 128 row-tiles of 128), block 256 (4 waves, 32 rows each, 64 cols).
__global__ __launch_bounds__(256) void proj_kernel(ProjArgs pa) {
  const int job = blockIdx.x;
  const int rb  = blockIdx.y * 128;
  const int tid = threadIdx.x;
  const int lane = tid & 63, w = tid >> 6;
  const int l31 = lane & 31, lh = lane >> 5;
  const int l7 = lane & 7, l8 = lane >> 3;

  __shared__ __bf16 lds_b[64][264];      // 64 n x 256 k (+8 pad, 528B rows)
  __shared__ __bf16 lds_a[2][128 * 64];  // dbuf BK=64, swizzled 128B rows

  int src, dout, wc0[2], vcol0 = 0, vmode = 0;
  const float* wp[2];
  __bf16* dqk[2] = {nullptr, nullptr};
  __bf16* vdst = nullptr;
  float sc = 1.0f;
  if (job < 4) {
    dout = 32; wc0[0] = 0; wc0[1] = 0;
    switch (job) {
      case 0: src=0; wp[0]=pa.w[0]; wp[1]=pa.w[3];  dqk[0]=pa.q[0]; dqk[1]=pa.q[1]; sc=QSCALE; break;
      case 1: src=0; wp[0]=pa.w[1]; wp[1]=pa.w[10]; dqk[0]=pa.k[0]; dqk[1]=pa.k[3]; break;
      case 2: src=1; wp[0]=pa.w[6]; wp[1]=pa.w[9];  dqk[0]=pa.q[2]; dqk[1]=pa.q[3]; sc=QSCALE; break;
      default:src=1; wp[0]=pa.w[4]; wp[1]=pa.w[7];  dqk[0]=pa.k[1]; dqk[1]=pa.k[2]; break;
    }
  } else {
    const int vi = (job - 4) >> 2, t = (job - 4) & 3;
    const int widx = (vi==0) ? 2 : (vi==1) ? 11 : (vi==2) ? 5 : 8;   // w3,w12,w6,w9
    const int vbuf = (vi==0) ? 0 : (vi==1) ? 3  : (vi==2) ? 1 : 2;   // V0,V3,V1,V2
    dout = 256; vmode = 1; src = vi >> 1;                            // e,e,p,p
    wp[0] = pa.w[widx]; wp[1] = pa.w[widx];
    wc0[0] = t*64; wc0[1] = t*64 + 32;
    vcol0 = t*64; vdst = pa.vt[vbuf];
  }

  // stage B transposed (once): lds_b[n][k] = w[k][c0+n]
  for (int h = 0; h < 2; ++h) {
    const float* wgt = wp[h]; const int c0 = wc0[h];
    for (int i = tid; i < 32*256; i += 256) {
      int n = i & 31, kk = i >> 5;
      lds_b[h*32 + n][kk] = (__bf16)wgt[(size_t)kk*dout + c0 + n];
    }
  }

  const __bf16* X = src ? pa.xp : pa.xe;
  const char* agbase = (const char*)(X + (size_t)rb*256) + (size_t)(l7 ^ l8)*16
                     + (size_t)l8*512;

  // stage A slice kb into buf (rows (w*4+i)*8 + l8, swizzled chunk l7^l8)
#define STAGE_A(buf, kb)                                                        \
  {                                                                             \
    const char* g = agbase + (size_t)(kb)*128;                                  \
    _Pragma("unroll")                                                           \
    for (int i = 0; i < 4; ++i)                                                 \
      __builtin_amdgcn_global_load_lds(                                         \
          (gvoid*)(g + (size_t)(w*4 + i)*8*512),                                \
          (svoid*)&lds_a[buf][((w*4 + i)*8)*64 + lane*8], 16, 0, 0);            \
  }

  STAGE_A(0, 0)
  __syncthreads();

  v16f acc[2];
#pragma unroll
  for (int n = 0; n < 2; ++n)
#pragma unroll
    for (int i = 0; i < 16; ++i) acc[n][i] = 0.f;

  for (int kb = 0; kb < 4; ++kb) {
    if (kb < 3) STAGE_A((kb + 1) & 1, kb + 1)
    const __bf16* ab = &lds_a[kb & 1][0];
#pragma unroll
    for (int kk = 0; kk < 4; ++kk) {
      const v8bf af = *(const v8bf*)&ab[(w*32 + l31)*64 + (((kk*2 + lh) ^ (l31 & 7))*8)];
#pragma unroll
      for (int nt = 0; nt < 2; ++nt) {
        const v8bf bf = *(const v8bf*)&lds_b[nt*32 + l31][kb*64 + kk*16 + lh*8];
        acc[nt] = __builtin_amdgcn_mfma_f32_32x32x16_bf16(af, bf, acc[nt], 0, 0, 0);
      }
    }
    __syncthreads();
  }

  if (!vmode) {
    // Q/K row-major [16384][32]
#pragma unroll
    for (int nt = 0; nt < 2; ++nt) {
      __bf16* dst = dqk[nt];
#pragma unroll
      for (int r = 0; r < 16; ++r) {
        const int row = rb + w*32 + (r & 3) + 8*(r >> 2) + 4*lh;
        dst[(size_t)row*32 + l31] = (__bf16)(acc[nt][r] * sc);
      }
    }
  } else {
    // V: transpose through LDS (reuse lds_a), then write GLOBAL FRAGMENT-SLOT
    // layout: Vf[(bb*32+kt)*2048 + ((nt)*8 + kc2)*32 + v5] 16B slots.
    // Block owns vcols [vcol0, vcol0+64) and keys [ll0, ll0+128) (2 kt tiles,
    // 512 contiguous slots each) -> 256 consecutive tids write 4KB contiguous.
    __bf16 (*lds_t)[136] = (__bf16 (*)[136])&lds_a[0][0];  // 64 x 136 (272B rows)
#pragma unroll
    for (int nt = 0; nt < 2; ++nt) {
#pragma unroll
      for (int r = 0; r < 16; ++r) {
        const int row = w*32 + (r & 3) + 8*(r >> 2) + 4*lh;
        lds_t[nt*32 + l31][row] = (__bf16)acc[nt][r];
      }
    }
    __syncthreads();
    const int bb = rb >> 11, ll0 = rb & 2047;
    const int nt0 = vcol0 >> 5;                       // t*2
    const size_t tbase = (size_t)(bb*32 + (ll0 >> 6));
    for (int i = tid; i < 1024; i += 256) {
      const int ktl = i >> 9, s = i & 511;
      const int h = s >> 8, kc2 = (s >> 5) & 7, v5 = s & 31;
      const int vrow = h*32 + v5, krow = ktl*64 + kc2*8;
      *(int4*)&vdst[((tbase + ktl)*2048 + (size_t)((nt0 + h)*8 + kc2)*32 + v5) * 8] =
          *(const int4*)&lds_t[vrow][krow];
    }
  }
}

// ---------------------------------------------------------------- flash attention
struct FlashArgs {
  const __bf16* q[4];
  const __bf16* k[4];
  const __bf16* v[4];
  const float* alpha;
  const float* gamma;
  float* out;
};

// 512 blocks x 256 thr. flat = pair + 32*qt (pair%8 pins an (att,bb) to one XCD).
// Wave: 32 q x 256 vcols over 32 kt of 64 keys. V tile (32KB, fragment-slot
// order in GLOBAL memory) dbuf-staged via global_load_lds: per instr the wave
// reads 1KB contiguous global and deposits 1KB linear LDS. PV ds_read_b128:
// slots nt*256 + kc*64 + lane -> contiguous 1KB, zero conflicts, imm offsets.
__global__ __launch_bounds__(256, 2) void flash_kernel(FlashArgs fa) {
  const int flat = blockIdx.x;
  const int pair = flat & 31, qt = flat >> 5;
  const int att = pair & 3, bb = pair >> 2;
  const int tid = threadIdx.x;
  const int lane = tid & 63, w = tid >> 6;
  const int l31 = lane & 31, lh = lane >> 5;

  __shared__ __bf16 v_lds[2][16384];  // 2 x 2048 slots x 16B, frag order

  const __bf16* Q  = fa.q[att] + (size_t)bb*2048*32;
  const __bf16* Kb = fa.k[att] + (size_t)bb*2048*32;
  const __bf16* Vb = fa.v[att] + (size_t)bb*32*16384;   // 32 kt tiles x 2048 slots
  float scv = 1.0f;
  if (att == 0) scv = fa.alpha[0];
  if (att == 2) scv = fa.gamma[0];
  const int zcol = (att >> 1) * 256;

  // Q B-frags (resident): B[n=q=l31][k=d = c*16 + lh*8 + j]
  const int qrow = qt*128 + w*32 + l31;
  const v8bf qf0 = *(const v8bf*)&Q[(size_t)qrow*32 + lh*8];
  const v8bf qf1 = *(const v8bf*)&Q[(size_t)qrow*32 + 16 + lh*8];

  // V staging: wave w stages slots [512w, 512w+512); instr i covers slots
  // 512w+64i+lane -> global source contiguous 16B/lane (1KB/instr), LDS linear.
  const char* vgbase = (const char*)Vb + (size_t)(512*w + lane)*16;

#define STAGE_V(buf, kt_)                                                       \
  {                                                                             \
    const char* g = vgbase + (size_t)(kt_)*32768;                               \
    _Pragma("unroll")                                                           \
    for (int i = 0; i < 8; ++i)                                                 \
      __builtin_amdgcn_global_load_lds(                                         \
          (gvoid*)(g + (size_t)i*1024),                                         \
          (svoid*)&v_lds[buf][(512*w + 64*i)*8 + lane*8], 16, 0, 0);            \
  }

  v16f acc[8];
#pragma unroll
  for (int n = 0; n < 8; ++n)
#pragma unroll
    for (int i = 0; i < 16; ++i) acc[n][i] = 0.f;

  float den_s = 0.f;        // per-lane row-sum accumulator (q = l31, this lh-half's keys)
  v8bf pf[4];               // P A-frags for the CURRENT kt (made one iteration ahead)
  v8bf kf00, kf01, kf10, kf11;
  v16f st0, st1;
  u32 pk0[8], pk1[8];

  // K A-frags for tile kt_: A[m=key = t*32+l31][k=d]
#define LOADK(kt_)                                                              \
  {                                                                             \
    const int kb_ = (kt_) * 64;                                                 \
    kf00 = *(const v8bf*)&Kb[((size_t)(kb_ +      l31))*32 +      lh*8];        \
    kf01 = *(const v8bf*)&Kb[((size_t)(kb_ +      l31))*32 + 16 + lh*8];        \
    kf10 = *(const v8bf*)&Kb[((size_t)(kb_ + 32 + l31))*32 +      lh*8];        \
    kf11 = *(const v8bf*)&Kb[((size_t)(kb_ + 32 + l31))*32 + 16 + lh*8];        \
  }

  // S^T = K.Q^T (log2 domain): C[row=key][col=q]
#define SMFMA                                                                   \
  {                                                                             \
    _Pragma("unroll")                                                           \
    for (int i = 0; i < 16; ++i) { st0[i] = 0.f; st1[i] = 0.f; }                \
    st0 = __builtin_amdgcn_mfma_f32_32x32x16_bf16(kf00, qf0, st0, 0, 0, 0);     \
    st0 = __builtin_amdgcn_mfma_f32_32x32x16_bf16(kf01, qf1, st0, 0, 0, 0);     \
    st1 = __builtin_amdgcn_mfma_f32_32x32x16_bf16(kf10, qf0, st1, 0, 0, 0);     \
    st1 = __builtin_amdgcn_mfma_f32_32x32x16_bf16(kf11, qf1, st1, 0, 0, 0);     \
  }

  // P = exp2(S^T) into bf16-packed key-pair dwords; den_s accumulates row sums
#define EXPH(st_, pk_)                                                          \
  _Pragma("unroll")                                                             \
  for (int i = 0; i < 8; ++i) {                                                 \
    const float e0 = __builtin_exp2f(st_[2*i]);                                 \
    const float e1 = __builtin_exp2f(st_[2*i + 1]);                             \
    den_s += e0 + e1;                                                           \
    pk_[i] = pack_bf16(e0, e1);                                                 \
  }

  // P C-layout -> A-layout via lane-half exchange (v_permlane32_swap_b32:
  // vdst.upper <-> vsrc.lower), 2 VALU ops per 4 A-frag dwords.
#define XCHG(pk_, o_)                                                           \
  _Pragma("unroll")                                                             \
  for (int f2 = 0; f2 < 2; ++f2) {                                              \
    u32 a0 = pk_[f2*4 + 0], b0 = pk_[f2*4 + 2];                                 \
    u32 a1 = pk_[f2*4 + 1], b1 = pk_[f2*4 + 3];                                 \
    asm("v_permlane32_swap_b32 %0, %1" : "+v"(a0), "+v"(b0));                   \
    asm("v_permlane32_swap_b32 %0, %1" : "+v"(a1), "+v"(b1));                   \
    frag_u fu;                                                                  \
    fu.d[0] = a0; fu.d[1] = a1; fu.d[2] = b0; fu.d[3] = b1;                     \
    pf[(o_) + f2] = fu.v;                                                       \
  }

  // one kc-block of PV: 8 MFMAs over 8 vcol tiles; reads contiguous, offsets imm
#define PVBLK(kc_, vb_)                                                         \
  _Pragma("unroll")                                                             \
  for (int nt = 0; nt < 8; ++nt) {                                              \
    const v8bf vf = *(const v8bf*)&vb_[nt*2048 + (kc_)*512 + lane*8];           \
    acc[nt] = __builtin_amdgcn_mfma_f32_32x32x16_bf16(pf[kc_], vf, acc[nt], 0, 0, 0); \
  }

  // prologue: K first (its wait leaves stage loads in flight), stage V(0),
  // compute P(0) while staging is in flight
  LOADK(0)
  STAGE_V(0, 0)
  SMFMA
  EXPH(st0, pk0)
  EXPH(st1, pk1)
  XCHG(pk0, 0)
  XCHG(pk1, 2)
  __syncthreads();  // V(0) staged

  for (int kt = 0; kt < 31; ++kt) {
    const int cur = kt & 1;
    LOADK(kt + 1)              // issued before stage: kf wait = vmcnt(8), no drain
    STAGE_V(cur ^ 1, kt + 1)   // lands by end-of-iteration barrier
    const __bf16* vb = &v_lds[cur][0];

    PVBLK(0, vb)
    SMFMA                      // S(kt+1): independent of PV(kt)
    PVBLK(1, vb)
    EXPH(st0, pk0)             // softmax VALU hides under PV MFMA issue
    PVBLK(2, vb)
    EXPH(st1, pk1)
    XCHG(pk0, 0)               // pf[0..1] already consumed by PVBLK(0/1)
    PVBLK(3, vb)
    XCHG(pk1, 2)               // pf[2..3] consumed by PVBLK(2/3)

    __syncthreads();           // all waves done with v_lds[cur]; V(kt+1) staged
  }

  {
    // kt=31: PV only (cur = 1)
    const __bf16* vb = &v_lds[1][0];
    PVBLK(0, vb)
    PVBLK(1, vb)
    PVBLK(2, vb)
    PVBLK(3, vb)
  }

  // epilogue: den[q] = this half's sum + partner half's sum; broadcast by lane
  const float den_full = den_s + __shfl_xor(den_s, 32, 64);
  float* outp = fa.out + (size_t)(bb*2048 + qt*128 + w*32) * 512 + zcol;
#pragma unroll
  for (int r = 0; r < 16; ++r) {
    const int row = (r & 3) + 8*(r >> 2) + 4*lh;
    const float f = scv / __shfl(den_full, row, 64);
#pragma unroll
    for (int nt = 0; nt < 8; ++nt)
      unsafeAtomicAdd(&outp[(size_t)row*512 + nt*32 + l31], acc[nt][r] * f);
  }
}

// ---------------------------------------------------------------- launch
extern "C" void kernel_launch(void* const* d_in, const int* in_sizes, int n_in,
                              void* d_out, int out_size, void* d_ws, size_t ws_size,
                              hipStream_t stream) {
  (void)in_sizes; (void)n_in; (void)out_size; (void)ws_size;

  __bf16* wsp = (__bf16*)d_ws;
  const size_t XE = (size_t)16384 * 256;
  const size_t QK = (size_t)16384 * 32;
  const size_t VT = (size_t)8 * 32 * 16384;   // 8 bb x 32 kt x 2048 slots x 8

  __bf16* xe = wsp;
  __bf16* xp = wsp + XE;

  ProjArgs pa;
  pa.xe = xe; pa.xp = xp;
  const float* x = (const float*)d_in[0];
  for (int i = 0; i < 12; ++i) pa.w[i] = (const float*)d_in[1 + i];
  __bf16* base = wsp + 2*XE;
  for (int i = 0; i < 4; ++i) pa.q[i]  = base + (size_t)i * QK;
  for (int i = 0; i < 4; ++i) pa.k[i]  = base + (size_t)(4 + i) * QK;
  for (int i = 0; i < 4; ++i) pa.vt[i] = base + 8*QK + (size_t)i * VT;

  hipMemsetAsync(d_out, 0, (size_t)8*2048*512*4, stream);
  hipLaunchKernelGGL(deint_kernel, dim3(2048), dim3(256), 0, stream, x, xe, xp);
  hipLaunchKernelGGL(proj_kernel, dim3(20, 128), dim3(256), 0, stream, pa);

  FlashArgs fl;
  for (int i = 0; i < 4; ++i) { fl.q[i] = pa.q[i]; fl.k[i] = pa.k[i]; fl.v[i] = pa.vt[i]; }
  fl.alpha = (const float*)d_in[13];
  fl.gamma = (const float*)d_in[14];
  fl.out = (float*)d_out;
  hipLaunchKernelGGL(flash_kernel, dim3(512), dim3(256), 0, stream, fl);
}

// Round 7
// 228.991 us; speedup vs baseline: 1.3784x; 1.2395x over previous
//
#include <hip/hip_runtime.h>

// B=8, L=2048, C=256, D=32. Four attentions (ecg/pcg intra/inter),
// out = concat(inter + scalar*intra) -> (8,2048,512) f32.
//
// Pipeline:
//   1) hipMemsetAsync(d_out, 0); attentions atomically accumulate.
//   2) deint_kernel : x f32 interleaved -> xe, xp bf16 [16384][256]
//   3) proj_kernel  : xe/xp @ w -> bf16 Q[4] (pre-scaled log2e/sqrt(32)), K[4],
//      V in GLOBAL FRAGMENT-SLOT ORDER Vf[bb][kt64][slot]:
//        slot(nt,kc2,v5) = (nt*8+kc2)*32 + v5, 16B slots (8 keys), tile = 32KB.
//      alpha/gamma-gated V jobs (V0/w3, V2/w9) exit when the scalar is 0.
//   4) flash_kernel : 512 blocks x 256 thr (4 waves = 4 q-subtiles, 64-key tiles),
//      r4 structure (passed): V dbuf-staged via global_load_lds (1KB contiguous
//      global per instr, linear LDS, conflict-free contiguous ds_read_b128).
//      VCOL-SPLIT RETARGET: when alpha==0 the att0 block becomes an att1 block
//      covering vcol tiles 4..7 (nt0=4) while the att1 block covers tiles 0..3;
//      same for att2/att3 with gamma. Same keys, same per-wave softmax/den
//      (identical in both halves, block-local), half the PV/staging/ds work,
//      disjoint output columns. Body templated on NTN in {4,8}.
//      S^T trick: A=K,B=Q so each lane holds its query's keys; P -> MFMA-A via
//      v_permlane32_swap_b32 in r4's COPY form (do not tighten: suspected
//      VALU->permlane hazard when run in place on just-written pack results).
//      Fixed-max softmax in log2 domain; scalar den + shfl broadcast.
//      Epilogue: unsafeAtomicAdd.

typedef __bf16 v8bf __attribute__((ext_vector_type(8)));
typedef float  v16f __attribute__((ext_vector_type(16)));
typedef unsigned int u32;

typedef __attribute__((address_space(1))) const void gvoid;
typedef __attribute__((address_space(3))) void svoid;

#define QSCALE 0.25500526817276613f  // log2(e)/sqrt(32)

union frag_u { u32 d[4]; v8bf v; };
union pk_u { unsigned short s[2]; u32 d; };

static __device__ inline u32 pack_bf16(float x, float y) {
  pk_u u;
  __bf16 a = (__bf16)x, b = (__bf16)y;
  u.s[0] = *(unsigned short*)&a;
  u.s[1] = *(unsigned short*)&b;
  return u.d;
}

// ---------------------------------------------------------------- deinterleave
__global__ __launch_bounds__(256) void deint_kernel(const float* __restrict__ x,
                                                    __bf16* __restrict__ xe,
                                                    __bf16* __restrict__ xp) {
  const size_t i = (size_t)blockIdx.x * 256 + threadIdx.x;
  const float4* xin = (const float4*)(x + i * 16);
  float4 a = xin[0], b = xin[1], c = xin[2], d = xin[3];
  v8bf ev, pv;
  ev[0]=(__bf16)a.x; ev[1]=(__bf16)a.z; ev[2]=(__bf16)b.x; ev[3]=(__bf16)b.z;
  ev[4]=(__bf16)c.x; ev[5]=(__bf16)c.z; ev[6]=(__bf16)d.x; ev[7]=(__bf16)d.z;
  pv[0]=(__bf16)a.y; pv[1]=(__bf16)a.w; pv[2]=(__bf16)b.y; pv[3]=(__bf16)b.w;
  pv[4]=(__bf16)c.y; pv[5]=(__bf16)c.w; pv[6]=(__bf16)d.y; pv[7]=(__bf16)d.w;
  *(v8bf*)(xe + i * 8) = ev;
  *(v8bf*)(xp + i * 8) = pv;
}

// ---------------------------------------------------------------- projections
struct ProjArgs {
  const __bf16* xe;
  const __bf16* xp;
  const float* w[12];
  __bf16* q[4];
  __bf16* k[4];
  __bf16* vt[4];
  const float* alpha;
  const float* gamma;
};

// grid (20 jobs, 128 row-tiles of 128), block 256 (4 waves, 32 rows each, 64 cols).
__global__ __launch_bounds__(256) void proj_kernel(ProjArgs pa) {
  const int job = blockIdx.x;
  const int rb  = blockIdx.y * 128;
  const int tid = threadIdx.x;
  const int lane = tid & 63, w = tid >> 6;
  const int l31 = lane & 31, lh = lane >> 5;
  const int l7 = lane & 7, l8 = lane >> 3;

  // alpha/gamma-gated V jobs: V0 (w3, jobs 4-7, vi=0) needs alpha!=0;
  // V2 (w9, jobs 16-19, vi=3) needs gamma!=0. 0*finite == 0 exactly.
  if (job >= 4) {
    const int vi = (job - 4) >> 2;
    if (vi == 0 && pa.alpha[0] == 0.0f) return;
    if (vi == 3 && pa.gamma[0] == 0.0f) return;
  }

  __shared__ __bf16 lds_b[64][264];      // 64 n x 256 k (+8 pad, 528B rows)
  __shared__ __bf16 lds_a[2][128 * 64];  // dbuf BK=64, swizzled 128B rows

  int src, dout, wc0[2], vcol0 = 0, vmode = 0;
  const float* wp[2];
  __bf16* dqk[2] = {nullptr, nullptr};
  __bf16* vdst = nullptr;
  float sc = 1.0f;
  if (job < 4) {
    dout = 32; wc0[0] = 0; wc0[1] = 0;
    switch (job) {
      case 0: src=0; wp[0]=pa.w[0]; wp[1]=pa.w[3];  dqk[0]=pa.q[0]; dqk[1]=pa.q[1]; sc=QSCALE; break;
      case 1: src=0; wp[0]=pa.w[1]; wp[1]=pa.w[10]; dqk[0]=pa.k[0]; dqk[1]=pa.k[3]; break;
      case 2: src=1; wp[0]=pa.w[6]; wp[1]=pa.w[9];  dqk[0]=pa.q[2]; dqk[1]=pa.q[3]; sc=QSCALE; break;
      default:src=1; wp[0]=pa.w[4]; wp[1]=pa.w[7];  dqk[0]=pa.k[1]; dqk[1]=pa.k[2]; break;
    }
  } else {
    const int vi = (job - 4) >> 2, t = (job - 4) & 3;
    const int widx = (vi==0) ? 2 : (vi==1) ? 11 : (vi==2) ? 5 : 8;   // w3,w12,w6,w9
    const int vbuf = (vi==0) ? 0 : (vi==1) ? 3  : (vi==2) ? 1 : 2;   // V0,V3,V1,V2
    dout = 256; vmode = 1; src = vi >> 1;                            // e,e,p,p
    wp[0] = pa.w[widx]; wp[1] = pa.w[widx];
    wc0[0] = t*64; wc0[1] = t*64 + 32;
    vcol0 = t*64; vdst = pa.vt[vbuf];
  }

  // stage B transposed (once): lds_b[n][k] = w[k][c0+n]
  for (int h = 0; h < 2; ++h) {
    const float* wgt = wp[h]; const int c0 = wc0[h];
    for (int i = tid; i < 32*256; i += 256) {
      int n = i & 31, kk = i >> 5;
      lds_b[h*32 + n][kk] = (__bf16)wgt[(size_t)kk*dout + c0 + n];
    }
  }

  const __bf16* X = src ? pa.xp : pa.xe;
  const char* agbase = (const char*)(X + (size_t)rb*256) + (size_t)(l7 ^ l8)*16
                     + (size_t)l8*512;

  // stage A slice kb into buf (rows (w*4+i)*8 + l8, swizzled chunk l7^l8)
#define STAGE_A(buf, kb)                                                        \
  {                                                                             \
    const char* g = agbase + (size_t)(kb)*128;                                  \
    _Pragma("unroll")                                                           \
    for (int i = 0; i < 4; ++i)                                                 \
      __builtin_amdgcn_global_load_lds(                                         \
          (gvoid*)(g + (size_t)(w*4 + i)*8*512),                                \
          (svoid*)&lds_a[buf][((w*4 + i)*8)*64 + lane*8], 16, 0, 0);            \
  }

  STAGE_A(0, 0)
  __syncthreads();

  v16f acc[2];
#pragma unroll
  for (int n = 0; n < 2; ++n)
#pragma unroll
    for (int i = 0; i < 16; ++i) acc[n][i] = 0.f;

  for (int kb = 0; kb < 4; ++kb) {
    if (kb < 3) STAGE_A((kb + 1) & 1, kb + 1)
    const __bf16* ab = &lds_a[kb & 1][0];
#pragma unroll
    for (int kk = 0; kk < 4; ++kk) {
      const v8bf af = *(const v8bf*)&ab[(w*32 + l31)*64 + (((kk*2 + lh) ^ (l31 & 7))*8)];
#pragma unroll
      for (int nt = 0; nt < 2; ++nt) {
        const v8bf bf = *(const v8bf*)&lds_b[nt*32 + l31][kb*64 + kk*16 + lh*8];
        acc[nt] = __builtin_amdgcn_mfma_f32_32x32x16_bf16(af, bf, acc[nt], 0, 0, 0);
      }
    }
    __syncthreads();
  }

  if (!vmode) {
    // Q/K row-major [16384][32]
#pragma unroll
    for (int nt = 0; nt < 2; ++nt) {
      __bf16* dst = dqk[nt];
#pragma unroll
      for (int r = 0; r < 16; ++r) {
        const int row = rb + w*32 + (r & 3) + 8*(r >> 2) + 4*lh;
        dst[(size_t)row*32 + l31] = (__bf16)(acc[nt][r] * sc);
      }
    }
  } else {
    // V: transpose through LDS (reuse lds_a), then write GLOBAL FRAGMENT-SLOT
    // layout: Vf[(bb*32+kt64)*2048 + (nt*8 + kc2)*32 + v5] 16B slots.
    __bf16 (*lds_t)[136] = (__bf16 (*)[136])&lds_a[0][0];  // 64 x 136 (272B rows)
#pragma unroll
    for (int nt = 0; nt < 2; ++nt) {
#pragma unroll
      for (int r = 0; r < 16; ++r) {
        const int row = w*32 + (r & 3) + 8*(r >> 2) + 4*lh;
        lds_t[nt*32 + l31][row] = (__bf16)acc[nt][r];
      }
    }
    __syncthreads();
    const int bb = rb >> 11, ll0 = rb & 2047;
    const int nt0 = vcol0 >> 5;                       // t*2
    const size_t tbase = (size_t)(bb*32 + (ll0 >> 6));
    for (int i = tid; i < 1024; i += 256) {
      const int ktl = i >> 9, s = i & 511;
      const int h = s >> 8, kc2 = (s >> 5) & 7, v5 = s & 31;
      const int vrow = h*32 + v5, krow = ktl*64 + kc2*8;
      *(int4*)&vdst[((tbase + ktl)*2048 + (size_t)((nt0 + h)*8 + kc2)*32 + v5) * 8] =
          *(const int4*)&lds_t[vrow][krow];
    }
  }
}

// ---------------------------------------------------------------- flash attention
struct FlashArgs {
  const __bf16* q[4];
  const __bf16* k[4];
  const __bf16* v[4];
  const float* alpha;
  const float* gamma;
  float* out;
};

// Body: one wave's 32 q rows x NTN vcol tiles over 32 kt of 64 keys (r4 schedule).
// Qp: this wave's q row base. vgbase: global staging base (incl. nt0, w, lane).
// lds0: base of 2*NTN*2048-slot double buffer. outp: output base (incl. w, zcol).
template<int NTN>
__device__ __forceinline__ void flash_body(
    const __bf16* __restrict__ Qp, const __bf16* __restrict__ Kb,
    const char* __restrict__ vgbase, float scv, float* __restrict__ outp,
    __bf16* __restrict__ lds0, int lane, int w, int l31, int lh) {

  __bf16* vb0 = lds0;
  __bf16* vb1 = lds0 + NTN*2048;   // NTN*256 slots per buffer

  // Q B-frags (resident): B[n=q=l31][k=d = c*16 + lh*8 + j]
  const v8bf qf0 = *(const v8bf*)&Qp[lh*8];
  const v8bf qf1 = *(const v8bf*)&Qp[16 + lh*8];

#define STAGE_V(dst_, kt_)                                                      \
  {                                                                             \
    const char* g = vgbase + (size_t)(kt_)*32768;                               \
    _Pragma("unroll")                                                           \
    for (int i = 0; i < NTN; ++i)                                               \
      __builtin_amdgcn_global_load_lds(                                         \
          (gvoid*)(g + (size_t)i*1024),                                         \
          (svoid*)&dst_[(w*NTN*64 + 64*i)*8 + lane*8], 16, 0, 0);               \
  }

  v16f acc[NTN];
#pragma unroll
  for (int n = 0; n < NTN; ++n)
#pragma unroll
    for (int i = 0; i < 16; ++i) acc[n][i] = 0.f;

  float den_s = 0.f;        // per-lane row-sum accumulator (q = l31)
  v8bf pf[4];               // P A-frags for the CURRENT kt (made one iter ahead)
  v8bf kf00, kf01, kf10, kf11;
  v16f st0, st1;
  u32 pk0[8], pk1[8];

  // K A-frags for tile kt_: A[m=key = t*32+l31][k=d]
#define LOADK(kt_)                                                              \
  {                                                                             \
    const int kb_ = (kt_) * 64;                                                 \
    kf00 = *(const v8bf*)&Kb[((size_t)(kb_ +      l31))*32 +      lh*8];        \
    kf01 = *(const v8bf*)&Kb[((size_t)(kb_ +      l31))*32 + 16 + lh*8];        \
    kf10 = *(const v8bf*)&Kb[((size_t)(kb_ + 32 + l31))*32 +      lh*8];        \
    kf11 = *(const v8bf*)&Kb[((size_t)(kb_ + 32 + l31))*32 + 16 + lh*8];        \
  }

  // S^T = K.Q^T (log2 domain): C[row=key][col=q]
#define SMFMA                                                                   \
  {                                                                             \
    _Pragma("unroll")                                                           \
    for (int i = 0; i < 16; ++i) { st0[i] = 0.f; st1[i] = 0.f; }                \
    st0 = __builtin_amdgcn_mfma_f32_32x32x16_bf16(kf00, qf0, st0, 0, 0, 0);     \
    st0 = __builtin_amdgcn_mfma_f32_32x32x16_bf16(kf01, qf1, st0, 0, 0, 0);     \
    st1 = __builtin_amdgcn_mfma_f32_32x32x16_bf16(kf10, qf0, st1, 0, 0, 0);     \
    st1 = __builtin_amdgcn_mfma_f32_32x32x16_bf16(kf11, qf1, st1, 0, 0, 0);     \
  }

  // P = exp2(S^T) into bf16-packed key-pair dwords; den_s accumulates row sums
#define EXPH(st_, pk_)                                                          \
  _Pragma("unroll")                                                             \
  for (int i = 0; i < 8; ++i) {                                                 \
    const float e0 = __builtin_exp2f(st_[2*i]);                                 \
    const float e1 = __builtin_exp2f(st_[2*i + 1]);                             \
    den_s += e0 + e1;                                                           \
    pk_[i] = pack_bf16(e0, e1);                                                 \
  }

  // P C-layout -> A-layout via lane-half exchange (v_permlane32_swap_b32:
  // vdst.upper <-> vsrc.lower). COPY form (r4-validated) -- keep the copies.
#define XCHG(pk_, o_)                                                           \
  _Pragma("unroll")                                                             \
  for (int f2 = 0; f2 < 2; ++f2) {                                              \
    u32 a0 = pk_[f2*4 + 0], b0 = pk_[f2*4 + 2];                                 \
    u32 a1 = pk_[f2*4 + 1], b1 = pk_[f2*4 + 3];                                 \
    asm("v_permlane32_swap_b32 %0, %1" : "+v"(a0), "+v"(b0));                   \
    asm("v_permlane32_swap_b32 %0, %1" : "+v"(a1), "+v"(b1));                   \
    frag_u fu;                                                                  \
    fu.d[0] = a0; fu.d[1] = a1; fu.d[2] = b0; fu.d[3] = b1;                     \
    pf[(o_) + f2] = fu.v;                                                       \
  }

  // one kc-block of PV: NTN MFMAs over NTN vcol tiles; contiguous, imm offsets
#define PVBLK(kc_, vb_)                                                         \
  _Pragma("unroll")                                                             \
  for (int nt = 0; nt < NTN; ++nt) {                                            \
    const v8bf vf = *(const v8bf*)&vb_[(nt*256 + (kc_)*64 + lane)*8];           \
    acc[nt] = __builtin_amdgcn_mfma_f32_32x32x16_bf16(pf[kc_], vf, acc[nt], 0, 0, 0); \
  }

  // prologue: K first (its wait leaves stage loads in flight), stage V(0),
  // compute P(0) while staging is in flight
  LOADK(0)
  STAGE_V(vb0, 0)
  SMFMA
  EXPH(st0, pk0)
  EXPH(st1, pk1)
  XCHG(pk0, 0)
  XCHG(pk1, 2)
  __syncthreads();  // V(0) staged

  for (int kt = 0; kt < 31; ++kt) {
    const int cur = kt & 1;
    LOADK(kt + 1)              // issued before stage: kf wait = counted, no drain
    if (cur) { STAGE_V(vb0, kt + 1) } else { STAGE_V(vb1, kt + 1) }
    const __bf16* vb = cur ? vb1 : vb0;

    PVBLK(0, vb)
    SMFMA                      // S(kt+1): independent of PV(kt)
    PVBLK(1, vb)
    EXPH(st0, pk0)             // softmax VALU hides under PV MFMA issue
    PVBLK(2, vb)
    EXPH(st1, pk1)
    XCHG(pk0, 0)               // pf[0..1] already consumed by PVBLK(0/1)
    PVBLK(3, vb)
    XCHG(pk1, 2)               // pf[2..3] consumed by PVBLK(2/3)

    __syncthreads();           // all waves done with cur buffer; V(kt+1) staged
  }

  {
    // kt=31: PV only (cur = 1 -> vb1)
    PVBLK(0, vb1)
    PVBLK(1, vb1)
    PVBLK(2, vb1)
    PVBLK(3, vb1)
  }

  // epilogue: den[q] = this half's sum + partner half's sum; broadcast by lane
  const float den_full = den_s + __shfl_xor(den_s, 32, 64);
#pragma unroll
  for (int r = 0; r < 16; ++r) {
    const int row = (r & 3) + 8*(r >> 2) + 4*lh;
    const float f = scv / __shfl(den_full, row, 64);
#pragma unroll
    for (int nt = 0; nt < NTN; ++nt)
      unsafeAtomicAdd(&outp[(size_t)row*512 + nt*32 + l31], acc[nt][r] * f);
  }

#undef STAGE_V
#undef LOADK
#undef SMFMA
#undef EXPH
#undef XCHG
#undef PVBLK
}

// 512 blocks x 256 thr. flat = pair + 32*qt (pair%8 pins an (att,bb) to one XCD).
// Wave: 32 q x (NTN*32) vcols over 32 kt of 64 keys. When the gating scalar is 0,
// the intra block retargets to its partner inter attention's upper vcol half.
__global__ __launch_bounds__(256, 2) void flash_kernel(FlashArgs fa) {
  const int flat = blockIdx.x;
  const int pair = flat & 31, qt = flat >> 5;
  const int att = pair & 3, bb = pair >> 2;
  const int tid = threadIdx.x;
  const int lane = tid & 63, w = tid >> 6;
  const int l31 = lane & 31, lh = lane >> 5;

  __shared__ __bf16 v_lds[2][16384];  // 2 x 2048 slots x 16B (half used if NTN=4)

  const float av = fa.alpha[0], gv = fa.gamma[0];
  float scv = 1.0f;
  int att_e = att, nt0 = 0;
  bool half = false;
  if (att == 0)      { if (av == 0.0f) { att_e = 1; nt0 = 4; half = true; } else scv = av; }
  else if (att == 1) { half = (av == 0.0f); }
  else if (att == 2) { if (gv == 0.0f) { att_e = 3; nt0 = 4; half = true; } else scv = gv; }
  else               { half = (gv == 0.0f); }

  const __bf16* Qp = fa.q[att_e] + (size_t)(bb*2048 + qt*128 + w*32 + l31)*32;
  const __bf16* Kb = fa.k[att_e] + (size_t)bb*2048*32;
  const char* Vb   = (const char*)(fa.v[att_e] + (size_t)bb*32*16384);
  float* outp = fa.out + (size_t)(bb*2048 + qt*128 + w*32)*512
              + (att_e >> 1)*256 + nt0*32;

  if (half) {
    const char* vgbase = Vb + (size_t)(nt0*256 + w*256 + lane)*16;
    flash_body<4>(Qp, Kb, vgbase, scv, outp, &v_lds[0][0], lane, w, l31, lh);
  } else {
    const char* vgbase = Vb + (size_t)(w*512 + lane)*16;
    flash_body<8>(Qp, Kb, vgbase, scv, outp, &v_lds[0][0], lane, w, l31, lh);
  }
}

// ---------------------------------------------------------------- launch
extern "C" void kernel_launch(void* const* d_in, const int* in_sizes, int n_in,
                              void* d_out, int out_size, void* d_ws, size_t ws_size,
                              hipStream_t stream) {
  (void)in_sizes; (void)n_in; (void)out_size; (void)ws_size;

  __bf16* wsp = (__bf16*)d_ws;
  const size_t XE = (size_t)16384 * 256;
  const size_t QK = (size_t)16384 * 32;
  const size_t VT = (size_t)8 * 32 * 16384;   // 8 bb x 32 kt64 x 2048 slots x 8

  __bf16* xe = wsp;
  __bf16* xp = wsp + XE;

  ProjArgs pa;
  pa.xe = xe; pa.xp = xp;
  const float* x = (const float*)d_in[0];
  for (int i = 0; i < 12; ++i) pa.w[i] = (const float*)d_in[1 + i];
  __bf16* base = wsp + 2*XE;
  for (int i = 0; i < 4; ++i) pa.q[i]  = base + (size_t)i * QK;
  for (int i = 0; i < 4; ++i) pa.k[i]  = base + (size_t)(4 + i) * QK;
  for (int i = 0; i < 4; ++i) pa.vt[i] = base + 8*QK + (size_t)i * VT;
  pa.alpha = (const float*)d_in[13];
  pa.gamma = (const float*)d_in[14];

  hipMemsetAsync(d_out, 0, (size_t)8*2048*512*4, stream);
  hipLaunchKernelGGL(deint_kernel, dim3(2048), dim3(256), 0, stream, x, xe, xp);
  hipLaunchKernelGGL(proj_kernel, dim3(20, 128), dim3(256), 0, stream, pa);

  FlashArgs fl;
  for (int i = 0; i < 4; ++i) { fl.q[i] = pa.q[i]; fl.k[i] = pa.k[i]; fl.v[i] = pa.vt[i]; }
  fl.alpha = (const float*)d_in[13];
  fl.gamma = (const float*)d_in[14];
  fl.out = (float*)d_out;
  hipLaunchKernelGGL(flash_kernel, dim3(512), dim3(256), 0, stream, fl);
}